// Round 1
// 260.534 us; speedup vs baseline: 1.2861x; 1.2861x over previous
//
#include <hip/hip_runtime.h>
#include <stdint.h>

typedef unsigned short u16;
typedef __bf16 bf16x8 __attribute__((ext_vector_type(8)));
typedef float f32x4 __attribute__((ext_vector_type(4)));

// Sizes
// x:  [16][256][64][64] fp32
// w:  [256][128][4][4]  fp32
// out:[16][128][128][128] fp32
// x_t (ws): [16][66][66][256] bf16, spatially padded by 1 with zeros
// Wk  (ws): [2 p][4 tap][8 kc][2 q][128 co][32 ci] bf16
static const size_t XT_BYTES = (size_t)16 * 66 * 66 * 256 * 2; // 35,684,352
static const size_t WK_BYTES = (size_t)2 * 4 * 8 * 2 * 128 * 32 * 2; // 1,048,576

__device__ __forceinline__ u16 f2bf(float f) {
  unsigned u = __float_as_uint(f);
  unsigned r = (u + 0x7fff + ((u >> 16) & 1)) >> 16; // RNE
  return (u16)r;
}

// async 16B global->LDS
__device__ __forceinline__ void ld_g2l16(const u16* g, void* l) {
  __builtin_amdgcn_global_load_lds(
      (const __attribute__((address_space(1))) unsigned int*)(uintptr_t)g,
      (__attribute__((address_space(3))) unsigned int*)(unsigned int)(uintptr_t)l,
      16, 0, 0);
}

// full-rank 2-bit XOR swizzle: distinct slots for rows differing in bit2
__device__ __forceinline__ int swz4(int row) { return (row ^ (row >> 2)) & 3; }

// ---------------- prep: x fp32 NCHW -> bf16 padded NHWC ----------------
__global__ __launch_bounds__(256) void prep_x(const float* __restrict__ x,
                                              u16* __restrict__ xt) {
  __shared__ __align__(16) u16 sh[64 * 264]; // [iw][ci], pad 8 keeps 16B align
  const int t = threadIdx.x;
  const int ihp = blockIdx.x; // 0..65
  const int n = blockIdx.y;   // 0..15
  u16* xtn = xt + ((size_t)(n * 66 + ihp)) * 66 * 256;
  if (ihp == 0 || ihp == 65) {
    for (int j = 0; j < 9; ++j) {
      int idx = j * 256 + t;
      if (idx < 2112) ((uint4*)xtn)[idx] = make_uint4(0, 0, 0, 0);
    }
    return;
  }
  const int ih = ihp - 1;
  const int iw0 = (t & 15) * 4;
  const int cib = t >> 4; // 0..15
  const float* xb = x + (size_t)n * 1048576 + (size_t)ih * 64;
#pragma unroll
  for (int it = 0; it < 16; ++it) {
    int ci = it * 16 + cib;
    const float4 v = *(const float4*)(xb + (size_t)ci * 4096 + iw0);
    sh[(iw0 + 0) * 264 + ci] = f2bf(v.x);
    sh[(iw0 + 1) * 264 + ci] = f2bf(v.y);
    sh[(iw0 + 2) * 264 + ci] = f2bf(v.z);
    sh[(iw0 + 3) * 264 + ci] = f2bf(v.w);
  }
  __syncthreads();
#pragma unroll
  for (int j = 0; j < 8; ++j) {
    int idx = j * 256 + t;
    int iw = idx >> 5;    // 0..63
    int chunk = idx & 31; // 0..31
    uint4 v = *(const uint4*)&sh[iw * 264 + chunk * 8];
    *(uint4*)&xtn[(size_t)(iw + 1) * 256 + chunk * 8] = v;
  }
  if (t < 64) { // side borders iwp = 0, 65
    int iwp = (t >> 5) * 65;
    int chunk = t & 31;
    *(uint4*)&xtn[(size_t)iwp * 256 + chunk * 8] = make_uint4(0, 0, 0, 0);
  }
}

// ---------------- prep: weights -> [p][tap][kc][q][co][ci32] bf16 ----------------
__global__ __launch_bounds__(256) void prep_w(const float* __restrict__ w,
                                              u16* __restrict__ wk) {
  int id = blockIdx.x * 256 + threadIdx.x; // < 524288
  int ci5 = id & 31;
  int co = (id >> 5) & 127;
  int q = (id >> 12) & 1;
  int kc = (id >> 13) & 7;
  int tap = (id >> 16) & 3;
  int p = id >> 18;
  int ci = kc * 32 + ci5;
  int dh = tap >> 1, dw = tap & 1;
  int kh = 2 * dh + 1 - p;
  int kw = 2 * dw + 1 - q;
  wk[id] = f2bf(w[((ci * 128 + co) * 4 + kh) * 4 + kw]);
}

// ---------------- main: dual-parity implicit GEMM, 2-phase dbuf pipeline ---------
// Block: fixed (n, p, m-row pair). Computes BOTH q parities -> full contiguous
// 128-wide output rows (float2 stores). K loop: s = tap*8 + kc (32 steps of K=32).
// Per step stage: A = [2q][128co][32ci] (16 KB), B = [2 rows][66 iwp][32 ci]
// (8.25 KB, shared by both q via shifted windows). One raw barrier per step;
// next-step loads issued before compute (latency hidden under 32 MFMAs).
__global__ __launch_bounds__(256, 2) void gemm_ct(const u16* __restrict__ xt,
                                                  const u16* __restrict__ wk,
                                                  const float* __restrict__ bias,
                                                  float* __restrict__ out) {
  __shared__ __align__(16) u16 As[2][8192]; // [q][co][32ci], 16B-slot swizzled
  __shared__ __align__(16) u16 Bs[2][4224]; // [r][iwp][32ci], 16B-slot swizzled
  const int t = threadIdx.x;
  const int lane = t & 63;
  const int wv = t >> 6;
  const int wm = wv >> 1, wn = wv & 1; // co-half, m-row
  const int quad = lane >> 4, l15 = lane & 15;

  // bijective XCD swizzle (nwg=1024, %8==0): each XCD gets contiguous sid range
  const int id = blockIdx.x;
  const int sid = (id & 7) * 128 + (id >> 3);
  const int mt = sid & 31;
  const int n = (sid >> 5) & 15;
  const int p = sid >> 9;
  const int m0 = mt * 2;

  const u16* wkp = wk + (size_t)p * 262144;
  const u16* xtn = xt + (size_t)n * (66 * 66 * 256);

  // ---- staging decomposition (source-side swizzle, linear LDS dest) ----
  int aoffs[4];
#pragma unroll
  for (int it = 0; it < 4; ++it) {
    int c = it * 256 + t;
    int co = (c >> 2) & 127;
    aoffs[it] = (c >> 2) * 32 + ((c & 3) ^ swz4(co)) * 8;
  }
  int bsrc[3];
#pragma unroll
  for (int it = 0; it < 3; ++it) {
    int c = it * 256 + t; // it==2 only valid for t<16 (c<528)
    int r = (c >= 264) ? 1 : 0;
    int rem = c - 264 * r;
    int iwp = rem >> 2;
    bsrc[it] = r * 16896 + iwp * 256 + ((rem & 3) ^ swz4(iwp)) * 8;
  }

  // ---- fragment-read offsets (u16 units), swizzled ----
  int aro[2][4];
#pragma unroll
  for (int q = 0; q < 2; ++q)
#pragma unroll
    for (int i = 0; i < 4; ++i) {
      int co = wm * 64 + i * 16 + l15;
      aro[q][i] = (q * 128 + co) * 32 + (quad ^ swz4(co)) * 8;
    }
  int bro0[4], bro1[4], bro2[4]; // windows shift 0,1,2
#pragma unroll
  for (int j = 0; j < 4; ++j) {
    int b0 = j * 16 + l15;
    bro0[j] = wn * 2112 + b0 * 32 + (quad ^ swz4(b0)) * 8;
    bro1[j] = wn * 2112 + (b0 + 1) * 32 + (quad ^ swz4(b0 + 1)) * 8;
    bro2[j] = wn * 2112 + (b0 + 2) * 32 + (quad ^ swz4(b0 + 2)) * 8;
  }

  f32x4 acc[2][4][4];
#pragma unroll
  for (int q = 0; q < 2; ++q)
#pragma unroll
    for (int i = 0; i < 4; ++i)
#pragma unroll
      for (int j = 0; j < 4; ++j) acc[q][i][j] = (f32x4){0.f, 0.f, 0.f, 0.f};

  const int mpp1 = m0 + p + 1;

  auto stage = [&](int buf, int s) {
    const u16* asrc = wkp + (size_t)s * 8192;
    u16* Ad = &As[buf][0];
    u16* Bd = &Bs[buf][0];
#pragma unroll
    for (int it = 0; it < 4; ++it)
      ld_g2l16(asrc + aoffs[it], Ad + (it * 256 + t) * 8);
    const int dh = s >> 4; // tap>>1
    const u16* bbase = xtn + (size_t)(mpp1 - dh) * 16896 + (s & 7) * 32;
    ld_g2l16(bbase + bsrc[0], Bd + t * 8);
    ld_g2l16(bbase + bsrc[1], Bd + (256 + t) * 8);
    if (t < 16) ld_g2l16(bbase + bsrc[2], Bd + (512 + t) * 8);
  };

  // prologue
  stage(0, 0);
  asm volatile("s_waitcnt vmcnt(0)" ::: "memory");
  __builtin_amdgcn_s_barrier();
  asm volatile("" ::: "memory");

  int cur = 0;
  for (int s = 0; s < 32; ++s) {
    if (s + 1 < 32) stage(cur ^ 1, s + 1); // issue next-step loads first
    const int dw = (s >> 3) & 1;
    // q0 window shift = 1-dw, q1 shift = 2-dw (static-index blend, no scratch)
    int brq0[4], brq1[4];
#pragma unroll
    for (int j = 0; j < 4; ++j) {
      brq0[j] = dw ? bro0[j] : bro1[j];
      brq1[j] = dw ? bro1[j] : bro2[j];
    }
    const u16* Ac = &As[cur][0];
    const u16* Bc = &Bs[cur][0];
    {
      bf16x8 af0[4], bf0[4];
#pragma unroll
      for (int i = 0; i < 4; ++i) af0[i] = *(const bf16x8*)(Ac + aro[0][i]);
#pragma unroll
      for (int j = 0; j < 4; ++j) bf0[j] = *(const bf16x8*)(Bc + brq0[j]);
      __builtin_amdgcn_s_setprio(1);
#pragma unroll
      for (int i = 0; i < 4; ++i)
#pragma unroll
        for (int j = 0; j < 4; ++j)
          acc[0][i][j] = __builtin_amdgcn_mfma_f32_16x16x32_bf16(
              af0[i], bf0[j], acc[0][i][j], 0, 0, 0);
      __builtin_amdgcn_s_setprio(0);
      bf16x8 af1[4], bf1[4];
#pragma unroll
      for (int i = 0; i < 4; ++i) af1[i] = *(const bf16x8*)(Ac + aro[1][i]);
#pragma unroll
      for (int j = 0; j < 4; ++j) bf1[j] = *(const bf16x8*)(Bc + brq1[j]);
      __builtin_amdgcn_s_setprio(1);
#pragma unroll
      for (int i = 0; i < 4; ++i)
#pragma unroll
        for (int j = 0; j < 4; ++j)
          acc[1][i][j] = __builtin_amdgcn_mfma_f32_16x16x32_bf16(
              af1[i], bf1[j], acc[1][i][j], 0, 0, 0);
      __builtin_amdgcn_s_setprio(0);
    }
    // drain ds_reads BEFORE barrier (so next stage can't clobber pending reads),
    // drain this step's issued stage loads (they're read next iteration)
    asm volatile("s_waitcnt lgkmcnt(0) vmcnt(0)" ::: "memory");
    __builtin_amdgcn_s_barrier();
    asm volatile("" ::: "memory");
    cur ^= 1;
  }

  // ---- epilogue: paired-parity float2 stores (full contiguous lines) ----
  const int oh = 2 * (m0 + wn) + p;
  float bv[4][4];
#pragma unroll
  for (int i = 0; i < 4; ++i)
#pragma unroll
    for (int r = 0; r < 4; ++r) bv[i][r] = bias[wm * 64 + i * 16 + quad * 4 + r];
#pragma unroll
  for (int i = 0; i < 4; ++i)
#pragma unroll
    for (int j = 0; j < 4; ++j) {
      int l = j * 16 + l15;
#pragma unroll
      for (int r = 0; r < 4; ++r) {
        int co = wm * 64 + i * 16 + quad * 4 + r;
        float2 v;
        v.x = acc[0][i][j][r] + bv[i][r];
        v.y = acc[1][i][j][r] + bv[i][r];
        *(float2*)&out[(((size_t)n * 128 + co) * 128 + oh) * 128 + 2 * l] = v;
      }
    }
}

// ---------------- safety fallback (ws too small): direct fp32 ----------------
__global__ __launch_bounds__(256) void ct_fallback(const float* __restrict__ x,
                                                   const float* __restrict__ w,
                                                   const float* __restrict__ bias,
                                                   float* __restrict__ out) {
  size_t id = (size_t)blockIdx.x * 256 + threadIdx.x;
  if (id >= (size_t)16 * 128 * 128 * 128) return;
  int ow = (int)(id & 127), oh = (int)(id >> 7) & 127;
  int co = (int)(id >> 14) & 127, n = (int)(id >> 21);
  int pp = oh & 1, m = oh >> 1, qq = ow & 1, l = ow >> 1;
  float s = bias[co];
  for (int ci = 0; ci < 256; ++ci) {
    for (int dh = 0; dh < 2; ++dh) {
      int ih = m + pp - dh;
      if (ih < 0 || ih > 63) continue;
      int kh = 2 * dh + 1 - pp;
      for (int dw = 0; dw < 2; ++dw) {
        int iw = l + qq - dw;
        if (iw < 0 || iw > 63) continue;
        int kw = 2 * dw + 1 - qq;
        s += x[(((size_t)n * 256 + ci) * 64 + ih) * 64 + iw] *
             w[((ci * 128 + co) * 4 + kh) * 4 + kw];
      }
    }
  }
  out[id] = s;
}

extern "C" void kernel_launch(void* const* d_in, const int* in_sizes, int n_in,
                              void* d_out, int out_size, void* d_ws, size_t ws_size,
                              hipStream_t stream) {
  const float* x = (const float*)d_in[0];
  const float* w = (const float*)d_in[1];
  const float* bias = (const float*)d_in[2];
  float* out = (float*)d_out;
  if (ws_size >= XT_BYTES + WK_BYTES) {
    u16* xt = (u16*)d_ws;
    u16* wkb = (u16*)((char*)d_ws + XT_BYTES);
    hipLaunchKernelGGL(prep_x, dim3(66, 16), dim3(256), 0, stream, x, xt);
    hipLaunchKernelGGL(prep_w, dim3(2048), dim3(256), 0, stream, w, wkb);
    hipLaunchKernelGGL(gemm_ct, dim3(1024), dim3(256), 0, stream, xt, wkb, bias, out);
  } else {
    hipLaunchKernelGGL(ct_fallback, dim3(131072), dim3(256), 0, stream, x, w, bias, out);
  }
}

// Round 2
// 246.341 us; speedup vs baseline: 1.3602x; 1.0576x over previous
//
#include <hip/hip_runtime.h>
#include <stdint.h>

typedef unsigned short u16;
typedef __bf16 bf16x8 __attribute__((ext_vector_type(8)));
typedef float f32x4 __attribute__((ext_vector_type(4)));
typedef float f32x2 __attribute__((ext_vector_type(2)));

// Sizes
// x:  [16][256][64][64] fp32
// w:  [256][128][4][4]  fp32
// out:[16][128][128][128] fp32
// x_t (ws): [16][66][66][256] bf16, spatially padded by 1 with zeros
// Wk  (ws): [2 p][2 dh][8 kc][2 dw][2 q][128 co][32 ci] bf16  (dw innermost pair)
static const size_t XT_BYTES = (size_t)16 * 66 * 66 * 256 * 2; // 35,684,352
static const size_t WK_BYTES = (size_t)2 * 2 * 8 * 2 * 2 * 128 * 32 * 2; // 1,048,576

__device__ __forceinline__ u16 f2bf(float f) {
  unsigned u = __float_as_uint(f);
  unsigned r = (u + 0x7fff + ((u >> 16) & 1)) >> 16; // RNE
  return (u16)r;
}

// async 16B global->LDS
__device__ __forceinline__ void ld_g2l16(const u16* g, void* l) {
  __builtin_amdgcn_global_load_lds(
      (const __attribute__((address_space(1))) unsigned int*)(uintptr_t)g,
      (__attribute__((address_space(3))) unsigned int*)(unsigned int)(uintptr_t)l,
      16, 0, 0);
}

// full-rank 2-bit XOR swizzle
__device__ __forceinline__ int swz4(int row) { return (row ^ (row >> 2)) & 3; }

// ---------------- prep: x fp32 NCHW -> bf16 padded NHWC ----------------
// 4x4 register transpose: each thread loads 4 float4 (4 ci x 4 iw), packs
// ushort4 along ci -> b64 LDS writes (16/thread, conflict-free), then
// uint4 reads along ci -> coalesced global stores.
__global__ __launch_bounds__(256) void prep_x(const float* __restrict__ x,
                                              u16* __restrict__ xt) {
  __shared__ __align__(16) u16 sh[64 * 264]; // [iw][ci], pitch 264 (16B-aligned)
  const int t = threadIdx.x;
  const int ihp = blockIdx.x; // 0..65
  const int n = blockIdx.y;   // 0..15
  u16* xtn = xt + ((size_t)(n * 66 + ihp)) * 66 * 256;
  if (ihp == 0 || ihp == 65) {
    for (int j = 0; j < 9; ++j) {
      int idx = j * 256 + t;
      if (idx < 2112) ((uint4*)xtn)[idx] = make_uint4(0, 0, 0, 0);
    }
    return;
  }
  const int ih = ihp - 1;
  const int iw0 = (t & 15) * 4;
  const int cb = (t >> 4) * 4;  // ci quad base within each 64-group
  const int swz = (t & 3) << 3; // == ((iw>>2)&3)<<3 for this thread's iw range
  const float* xb = x + (size_t)n * 1048576 + (size_t)ih * 64 + iw0;
#pragma unroll
  for (int it = 0; it < 4; ++it) {
    int ci0 = it * 64 + cb;
    float4 v0 = *(const float4*)(xb + (size_t)(ci0 + 0) * 4096);
    float4 v1 = *(const float4*)(xb + (size_t)(ci0 + 1) * 4096);
    float4 v2 = *(const float4*)(xb + (size_t)(ci0 + 2) * 4096);
    float4 v3 = *(const float4*)(xb + (size_t)(ci0 + 3) * 4096);
    int col = ci0 ^ swz;
    ushort4 u;
    u.x = f2bf(v0.x); u.y = f2bf(v1.x); u.z = f2bf(v2.x); u.w = f2bf(v3.x);
    *(ushort4*)&sh[(iw0 + 0) * 264 + col] = u;
    u.x = f2bf(v0.y); u.y = f2bf(v1.y); u.z = f2bf(v2.y); u.w = f2bf(v3.y);
    *(ushort4*)&sh[(iw0 + 1) * 264 + col] = u;
    u.x = f2bf(v0.z); u.y = f2bf(v1.z); u.z = f2bf(v2.z); u.w = f2bf(v3.z);
    *(ushort4*)&sh[(iw0 + 2) * 264 + col] = u;
    u.x = f2bf(v0.w); u.y = f2bf(v1.w); u.z = f2bf(v2.w); u.w = f2bf(v3.w);
    *(ushort4*)&sh[(iw0 + 3) * 264 + col] = u;
  }
  __syncthreads();
#pragma unroll
  for (int j = 0; j < 8; ++j) {
    int idx = j * 256 + t;
    int iw = idx >> 5;    // 0..63
    int chunk = idx & 31; // 0..31
    uint4 v = *(const uint4*)&sh[iw * 264 + ((chunk ^ ((iw >> 2) & 3)) << 3)];
    *(uint4*)&xtn[(size_t)(iw + 1) * 256 + chunk * 8] = v;
  }
  if (t < 64) { // side borders iwp = 0, 65
    int iwp = (t >> 5) * 65;
    int chunk = t & 31;
    *(uint4*)&xtn[(size_t)iwp * 256 + chunk * 8] = make_uint4(0, 0, 0, 0);
  }
}

// ---------------- prep: weights -> [p][dh][kc][dw][q][co][ci32] bf16 ----------------
__global__ __launch_bounds__(256) void prep_w(const float* __restrict__ w,
                                              u16* __restrict__ wk) {
  int id = blockIdx.x * 256 + threadIdx.x; // < 524288
  int ci5 = id & 31;
  int co = (id >> 5) & 127;
  int q = (id >> 12) & 1;
  int dw = (id >> 13) & 1;
  int kc = (id >> 14) & 7;
  int dh = (id >> 17) & 1;
  int p = id >> 18;
  int ci = kc * 32 + ci5;
  int kh = 2 * dh + 1 - p;
  int kw = 2 * dw + 1 - q;
  wk[id] = f2bf(w[((ci * 128 + co) * 4 + kh) * 4 + kw]);
}

// ---------------- main: dual-parity implicit GEMM, paired-dw pipeline ---------
// K loop: 16 pairs (dh,kc); each pair = 2 steps (dw=0,1) sharing ONE B stage
// (dw only shifts the read window). B double-buffered, staged 2 steps before
// last use -> counted vmcnt (never 0 at even steps) hides HBM latency.
// Shift-1 B fragment shared by (q0,dw0) and (q1,dw1) -> carried in registers.
__global__ __launch_bounds__(256, 2) void gemm_ct(const u16* __restrict__ xt,
                                                  const u16* __restrict__ wk,
                                                  const float* __restrict__ bias,
                                                  float* __restrict__ out) {
  __shared__ __align__(16) u16 As[2][8192]; // [q][co][32ci], 16B-slot swizzled
  __shared__ __align__(16) u16 Bs[2][4224]; // [r][iwp 0..65][32ci], swizzled
  const int t = threadIdx.x;
  const int lane = t & 63;
  const int wv = t >> 6;
  const int wm = wv >> 1, wn = wv & 1; // co-half, m-row
  const int quad = lane >> 4, l15 = lane & 15;

  // bijective XCD swizzle (nwg=1024, %8==0)
  const int id = blockIdx.x;
  const int sid = (id & 7) * 128 + (id >> 3);
  const int mt = sid & 31;
  const int n = (sid >> 5) & 15;
  const int p = sid >> 9;
  const int m0 = mt * 2;

  const u16* wkp = wk + (size_t)p * 262144;
  const u16* xtn = xt + (size_t)n * (66 * 66 * 256);

  // ---- staging decomposition (source-side swizzle, linear LDS dest) ----
  int aoffs[4];
#pragma unroll
  for (int it = 0; it < 4; ++it) {
    int c = it * 256 + t;
    int co = (c >> 2) & 127;
    aoffs[it] = (c >> 2) * 32 + ((c & 3) ^ swz4(co)) * 8;
  }
  int bsrc[3];
#pragma unroll
  for (int it = 0; it < 3; ++it) {
    int c = it * 256 + t; // it==2 only active for t<16 (c<528)
    int r = (c >= 264) ? 1 : 0;
    int rem = c - 264 * r;
    int iwp = rem >> 2;
    bsrc[it] = r * 16896 + iwp * 256 + ((rem & 3) ^ swz4(iwp)) * 8;
  }

  // ---- fragment-read offsets (u16 units), swizzled ----
  int aro[2][4];
#pragma unroll
  for (int q = 0; q < 2; ++q)
#pragma unroll
    for (int i = 0; i < 4; ++i) {
      int co = wm * 64 + i * 16 + l15;
      aro[q][i] = (q * 128 + co) * 32 + (quad ^ swz4(co)) * 8;
    }
  int bro[3][4]; // window shifts 0,1,2
#pragma unroll
  for (int k = 0; k < 3; ++k)
#pragma unroll
    for (int j = 0; j < 4; ++j) {
      int b0 = j * 16 + l15 + k;
      bro[k][j] = wn * 2112 + b0 * 32 + (quad ^ swz4(b0)) * 8;
    }

  f32x4 acc[2][4][4];
#pragma unroll
  for (int q = 0; q < 2; ++q)
#pragma unroll
    for (int i = 0; i < 4; ++i)
#pragma unroll
      for (int j = 0; j < 4; ++j) acc[q][i][j] = (f32x4){0.f, 0.f, 0.f, 0.f};

  const int mpp1 = m0 + p + 1;

  auto stageA = [&](int buf, int s) { // s = dh*16 + kc*2 + dw
    const u16* asrc = wkp + (size_t)s * 8192;
    u16* Ad = &As[buf][0];
#pragma unroll
    for (int it = 0; it < 4; ++it)
      ld_g2l16(asrc + aoffs[it], Ad + (it * 256 + t) * 8);
  };
  auto stageB = [&](int buf, int pr) { // pr = dh*8 + kc
    const int kc = pr & 7, dh = pr >> 3;
    const u16* bbase = xtn + (size_t)(mpp1 - dh) * 16896 + kc * 32;
    u16* Bd = &Bs[buf][0];
    ld_g2l16(bbase + bsrc[0], Bd + t * 8);
    ld_g2l16(bbase + bsrc[1], Bd + (256 + t) * 8);
    if (t < 16) ld_g2l16(bbase + bsrc[2], Bd + (512 + t) * 8);
  };

  // prologue
  stageA(0, 0);
  stageB(0, 0);
  asm volatile("s_waitcnt vmcnt(0)" ::: "memory");
  __builtin_amdgcn_s_barrier();
  asm volatile("" ::: "memory");

  bf16x8 keep[4]; // shift-1 B fragment, shared by (q0,dw0) and (q1,dw1)
#pragma unroll 1
  for (int pr = 0; pr < 16; ++pr) {
    const u16* Bc = &Bs[pr & 1][0];
    // ---- even step: s = 2*pr (dw=0): q0 uses shift1 (keep), q1 shift2 ----
    {
      stageA(1, 2 * pr + 1);
      __builtin_amdgcn_sched_barrier(0);
      if (pr < 15) stageB((pr + 1) & 1, pr + 1);
      __builtin_amdgcn_sched_barrier(0);
      const u16* Ac = &As[0][0];
      bf16x8 a0[4];
#pragma unroll
      for (int i = 0; i < 4; ++i) a0[i] = *(const bf16x8*)(Ac + aro[0][i]);
#pragma unroll
      for (int j = 0; j < 4; ++j) keep[j] = *(const bf16x8*)(Bc + bro[1][j]);
      __builtin_amdgcn_s_setprio(1);
#pragma unroll
      for (int i = 0; i < 4; ++i)
#pragma unroll
        for (int j = 0; j < 4; ++j)
          acc[0][i][j] = __builtin_amdgcn_mfma_f32_16x16x32_bf16(
              a0[i], keep[j], acc[0][i][j], 0, 0, 0);
      __builtin_amdgcn_s_setprio(0);
      bf16x8 a1[4], b2[4];
#pragma unroll
      for (int i = 0; i < 4; ++i) a1[i] = *(const bf16x8*)(Ac + aro[1][i]);
#pragma unroll
      for (int j = 0; j < 4; ++j) b2[j] = *(const bf16x8*)(Bc + bro[2][j]);
      __builtin_amdgcn_s_setprio(1);
#pragma unroll
      for (int i = 0; i < 4; ++i)
#pragma unroll
        for (int j = 0; j < 4; ++j)
          acc[1][i][j] = __builtin_amdgcn_mfma_f32_16x16x32_bf16(
              a1[i], b2[j], acc[1][i][j], 0, 0, 0);
      __builtin_amdgcn_s_setprio(0);
      // A(s+1) landed; leave this wave's B(pr+1) loads in flight (counted)
      if (pr < 15) {
        if (wv == 0)
          asm volatile("s_waitcnt lgkmcnt(0) vmcnt(3)" ::: "memory");
        else
          asm volatile("s_waitcnt lgkmcnt(0) vmcnt(2)" ::: "memory");
      } else {
        asm volatile("s_waitcnt lgkmcnt(0) vmcnt(0)" ::: "memory");
      }
      __builtin_amdgcn_s_barrier();
      asm volatile("" ::: "memory");
    }
    // ---- odd step: s = 2*pr+1 (dw=1): q0 uses shift0, q1 reuses keep ----
    {
      if (pr < 15) stageA(0, 2 * pr + 2);
      __builtin_amdgcn_sched_barrier(0);
      const u16* Ac = &As[1][0];
      bf16x8 a0[4], b0[4];
#pragma unroll
      for (int i = 0; i < 4; ++i) a0[i] = *(const bf16x8*)(Ac + aro[0][i]);
#pragma unroll
      for (int j = 0; j < 4; ++j) b0[j] = *(const bf16x8*)(Bc + bro[0][j]);
      __builtin_amdgcn_s_setprio(1);
#pragma unroll
      for (int i = 0; i < 4; ++i)
#pragma unroll
        for (int j = 0; j < 4; ++j)
          acc[0][i][j] = __builtin_amdgcn_mfma_f32_16x16x32_bf16(
              a0[i], b0[j], acc[0][i][j], 0, 0, 0);
      __builtin_amdgcn_s_setprio(0);
      bf16x8 a1[4];
#pragma unroll
      for (int i = 0; i < 4; ++i) a1[i] = *(const bf16x8*)(Ac + aro[1][i]);
      __builtin_amdgcn_s_setprio(1);
#pragma unroll
      for (int i = 0; i < 4; ++i)
#pragma unroll
        for (int j = 0; j < 4; ++j)
          acc[1][i][j] = __builtin_amdgcn_mfma_f32_16x16x32_bf16(
              a1[i], keep[j], acc[1][i][j], 0, 0, 0);
      __builtin_amdgcn_s_setprio(0);
      // drain everything: A(next even) + B(next pair) must be ready
      asm volatile("s_waitcnt lgkmcnt(0) vmcnt(0)" ::: "memory");
      __builtin_amdgcn_s_barrier();
      asm volatile("" ::: "memory");
    }
  }

  // ---- epilogue: paired-parity nontemporal float2 stores ----
  const int oh = 2 * (m0 + wn) + p;
#pragma unroll
  for (int i = 0; i < 4; ++i) {
#pragma unroll
    for (int j = 0; j < 4; ++j) {
      int l = j * 16 + l15;
#pragma unroll
      for (int r = 0; r < 4; ++r) {
        int co = wm * 64 + i * 16 + quad * 4 + r;
        float bv = bias[co];
        f32x2 v;
        v.x = acc[0][i][j][r] + bv;
        v.y = acc[1][i][j][r] + bv;
        __builtin_nontemporal_store(
            v, (f32x2*)&out[(((size_t)n * 128 + co) * 128 + oh) * 128 + 2 * l]);
      }
    }
  }
}

// ---------------- safety fallback (ws too small): direct fp32 ----------------
__global__ __launch_bounds__(256) void ct_fallback(const float* __restrict__ x,
                                                   const float* __restrict__ w,
                                                   const float* __restrict__ bias,
                                                   float* __restrict__ out) {
  size_t id = (size_t)blockIdx.x * 256 + threadIdx.x;
  if (id >= (size_t)16 * 128 * 128 * 128) return;
  int ow = (int)(id & 127), oh = (int)(id >> 7) & 127;
  int co = (int)(id >> 14) & 127, n = (int)(id >> 21);
  int pp = oh & 1, m = oh >> 1, qq = ow & 1, l = ow >> 1;
  float s = bias[co];
  for (int ci = 0; ci < 256; ++ci) {
    for (int dh = 0; dh < 2; ++dh) {
      int ih = m + pp - dh;
      if (ih < 0 || ih > 63) continue;
      int kh = 2 * dh + 1 - pp;
      for (int dw = 0; dw < 2; ++dw) {
        int iw = l + qq - dw;
        if (iw < 0 || iw > 63) continue;
        int kw = 2 * dw + 1 - qq;
        s += x[(((size_t)n * 256 + ci) * 64 + ih) * 64 + iw] *
             w[((ci * 128 + co) * 4 + kh) * 4 + kw];
      }
    }
  }
  out[id] = s;
}

extern "C" void kernel_launch(void* const* d_in, const int* in_sizes, int n_in,
                              void* d_out, int out_size, void* d_ws, size_t ws_size,
                              hipStream_t stream) {
  const float* x = (const float*)d_in[0];
  const float* w = (const float*)d_in[1];
  const float* bias = (const float*)d_in[2];
  float* out = (float*)d_out;
  if (ws_size >= XT_BYTES + WK_BYTES) {
    u16* xt = (u16*)d_ws;
    u16* wkb = (u16*)((char*)d_ws + XT_BYTES);
    hipLaunchKernelGGL(prep_x, dim3(66, 16), dim3(256), 0, stream, x, xt);
    hipLaunchKernelGGL(prep_w, dim3(2048), dim3(256), 0, stream, w, wkb);
    hipLaunchKernelGGL(gemm_ct, dim3(1024), dim3(256), 0, stream, xt, wkb, bias, out);
  } else {
    hipLaunchKernelGGL(ct_fallback, dim3(131072), dim3(256), 0, stream, x, w, bias, out);
  }
}